// Round 2
// baseline (47714.957 us; speedup 1.0000x reference)
//
#include <hip/hip_runtime.h>
#include <hip/hip_cooperative_groups.h>

namespace cg = cooperative_groups;

#define T_STEPS 512
#define H_DIM   2048
#define G_DIM   8192   // 4*H
#define NGUESS  4096

__device__ __forceinline__ float sigf(float x) { return 1.0f / (1.0f + expf(-x)); }

// ---------------------------------------------------------------------------
// Kernel 1: gather embeddings -> xs[T][2048]
// ---------------------------------------------------------------------------
__global__ void embed_kernel(const int* __restrict__ guesses,
                             const int* __restrict__ feedbacks,
                             const float* __restrict__ gemb,
                             const float* __restrict__ femb,
                             float* __restrict__ xs) {
    int t = blockIdx.x;                      // 512 blocks
    int g = guesses[t];
    int f = feedbacks[t];
    const float4* gs = (const float4*)(gemb + (size_t)g * 1024);
    const float4* fs = (const float4*)(femb + (size_t)f * 1024);
    float4* xg = (float4*)(xs + (size_t)t * H_DIM);
    int tid = threadIdx.x;                   // 256 threads
    xg[tid]       = gs[tid];
    xg[256 + tid] = fs[tid];
}

// ---------------------------------------------------------------------------
// Kernel 2: GX[t][r] = dot(W_ih[r], xs[t]) + b_ih[r] + b_hh[r]
// ---------------------------------------------------------------------------
__global__ void gx_gemm(const float* __restrict__ xs,
                        const float* __restrict__ Wih,
                        const float* __restrict__ bih,
                        const float* __restrict__ bhh,
                        float* __restrict__ GX) {
    __shared__ float As[64][17];
    __shared__ float Bs[64][17];
    int r0 = blockIdx.x * 64;
    int t0 = blockIdx.y * 64;
    int tid = threadIdx.x;
    int tx = tid & 15;
    int ty = tid >> 4;
    int lr = tid >> 2;
    int lk = (tid & 3) * 4;
    float acc[4][4] = {};

    for (int k0 = 0; k0 < H_DIM; k0 += 16) {
        const float* xp = xs  + (size_t)(t0 + lr) * H_DIM + k0 + lk;
        const float* wp = Wih + (size_t)(r0 + lr) * H_DIM + k0 + lk;
        As[lr][lk + 0] = xp[0]; As[lr][lk + 1] = xp[1];
        As[lr][lk + 2] = xp[2]; As[lr][lk + 3] = xp[3];
        Bs[lr][lk + 0] = wp[0]; Bs[lr][lk + 1] = wp[1];
        Bs[lr][lk + 2] = wp[2]; Bs[lr][lk + 3] = wp[3];
        __syncthreads();
#pragma unroll
        for (int kk = 0; kk < 16; ++kk) {
            float a[4], b[4];
#pragma unroll
            for (int i = 0; i < 4; ++i) a[i] = As[ty * 4 + i][kk];
#pragma unroll
            for (int j = 0; j < 4; ++j) b[j] = Bs[tx * 4 + j][kk];
#pragma unroll
            for (int i = 0; i < 4; ++i)
#pragma unroll
                for (int j = 0; j < 4; ++j) acc[i][j] += a[i] * b[j];
        }
        __syncthreads();
    }
#pragma unroll
    for (int i = 0; i < 4; ++i)
#pragma unroll
        for (int j = 0; j < 4; ++j) {
            int t = t0 + ty * 4 + i;
            int r = r0 + tx * 4 + j;
            GX[(size_t)t * G_DIM + r] = acc[i][j] + bih[r] + bhh[r];
        }
}

// ---------------------------------------------------------------------------
// Kernel 3: cooperative sequential LSTM loop, W_hh register-resident.
// 256 WGs x 1024 threads (16 waves, <=128 VGPR @ 4 waves/SIMD).
// WG w owns units [w*8, w*8+8) -> 32 gate rows. Wave v owns rows 2v, 2v+1.
// Lane l holds row elements {j*64+l : j=0..31} in VGPRs (64 regs).
// Per step: stage h (8KB) to LDS, 32 LDS reads + 64 FMA, 64-lane reduce,
// activations, agent-scope h store, grid.sync.
// ---------------------------------------------------------------------------
__global__ void __launch_bounds__(1024, 4)
lstm_loop(const float* __restrict__ Whh,
          const float* __restrict__ GX,
          const float* __restrict__ xs,
          float* __restrict__ hbuf) {
    cg::grid_group grid = cg::this_grid();
    __shared__ float h_lds[H_DIM];
    __shared__ float gates[32];

    const int wg   = blockIdx.x;        // 256
    const int base = wg * 8;            // unit base
    const int tid  = threadIdx.x;
    const int lane = tid & 63;
    const int wv   = tid >> 6;          // wave 0..15

    // rows owned by this wave: r_idx = gate*8 + unit
    const int r0 = 2 * wv;
    const int r1 = 2 * wv + 1;
    const int grow0 = (r0 >> 3) * H_DIM + base + (r0 & 7);   // global gate row
    const int grow1 = (r1 >> 3) * H_DIM + base + (r1 & 7);

    // ---- preload W_hh rows into registers (interleaved: elem j*64+lane) ----
    float w0[32], w1[32];
    {
        const float* W0 = Whh + (size_t)grow0 * H_DIM + lane;
        const float* W1 = Whh + (size_t)grow1 * H_DIM + lane;
#pragma unroll
        for (int j = 0; j < 32; ++j) {
            w0[j] = W0[j * 64];
            w1[j] = W1[j * 64];
        }
    }

    // zero h for step 0 (hbuf parity 0)
    if (tid < 8)
        __hip_atomic_store(hbuf + base + tid, 0.0f,
                           __ATOMIC_RELAXED, __HIP_MEMORY_SCOPE_AGENT);
    __threadfence();
    grid.sync();

    for (int t = 0; t < T_STEPS; ++t) {
        const float* h  = hbuf + (size_t)(t & 1) * H_DIM;
        const float* gx = GX + (size_t)t * G_DIM;
        // prefetch GX values early (needed only after the dot)
        float gxv0 = gx[grow0];
        float gxv1 = gx[grow1];

        // stage h into LDS (agent-scope loads: cross-XCD coherent)
        for (int i = tid; i < H_DIM; i += 1024)
            h_lds[i] = __hip_atomic_load(h + i, __ATOMIC_RELAXED,
                                         __HIP_MEMORY_SCOPE_AGENT);
        __syncthreads();

        float acc0 = 0.0f, acc1 = 0.0f;
#pragma unroll
        for (int j = 0; j < 32; ++j) {
            float hv = h_lds[j * 64 + lane];   // 2 lanes/bank: conflict-free
            acc0 += w0[j] * hv;
            acc1 += w1[j] * hv;
        }
#pragma unroll
        for (int off = 32; off > 0; off >>= 1) {
            acc0 += __shfl_xor(acc0, off, 64);
            acc1 += __shfl_xor(acc1, off, 64);
        }
        if (lane == 0) {
            gates[r0] = acc0 + gxv0;
            gates[r1] = acc1 + gxv1;
        }
        __syncthreads();

        if (tid < 8) {
            int u = tid;
            float gi = gates[0 * 8 + u];
            float gf = gates[1 * 8 + u];
            float gg = gates[2 * 8 + u];
            float go = gates[3 * 8 + u];
            float c_in = (t > 0) ? xs[(size_t)t * H_DIM + base + u] : 0.0f;
            float c  = sigf(gf) * c_in + sigf(gi) * tanhf(gg);
            float hn = sigf(go) * tanhf(c);
            __hip_atomic_store(hbuf + (size_t)((t + 1) & 1) * H_DIM + base + u,
                               hn, __ATOMIC_RELAXED, __HIP_MEMORY_SCOPE_AGENT);
        }
        __threadfence();
        grid.sync();
    }
}

// ---------------------------------------------------------------------------
// Kernel 4: logits[r] = dot(W_fc[r], h) + b_fc[r]
// ---------------------------------------------------------------------------
__global__ void fc_kernel(const float* __restrict__ Wfc,
                          const float* __restrict__ bfc,
                          const float* __restrict__ h,
                          float* __restrict__ logits) {
    int wg = blockIdx.x;           // 256
    int tid = threadIdx.x;
    int lane = tid & 63, wv = tid >> 6;
    int r0 = wg * 16;
    const float4* hv = (const float4*)h;
    for (int rr = wv; rr < 16; rr += 4) {
        int r = r0 + rr;
        const float4* wrow = (const float4*)(Wfc + (size_t)r * H_DIM);
        float acc = 0.0f;
#pragma unroll
        for (int c = 0; c < 8; ++c) {
            float4 w4 = wrow[c * 64 + lane];
            float4 h4 = hv[c * 64 + lane];
            acc += w4.x * h4.x + w4.y * h4.y + w4.z * h4.z + w4.w * h4.w;
        }
#pragma unroll
        for (int off = 32; off > 0; off >>= 1) acc += __shfl_xor(acc, off, 64);
        if (lane == 0) logits[r] = acc + bfc[r];
    }
}

// ---------------------------------------------------------------------------
// Kernel 5: softmax over 4096 logits -> out
// ---------------------------------------------------------------------------
__global__ void softmax_kernel(const float* __restrict__ logits,
                               float* __restrict__ out) {
    __shared__ float sm[8];
    int tid = threadIdx.x, lane = tid & 63, wv = tid >> 6;
    float m = -1e30f;
    for (int i = tid; i < NGUESS; i += 256) m = fmaxf(m, logits[i]);
#pragma unroll
    for (int off = 32; off > 0; off >>= 1) m = fmaxf(m, __shfl_xor(m, off, 64));
    if (lane == 0) sm[wv] = m;
    __syncthreads();
    m = fmaxf(fmaxf(sm[0], sm[1]), fmaxf(sm[2], sm[3]));
    float s = 0.0f;
    for (int i = tid; i < NGUESS; i += 256) s += expf(logits[i] - m);
#pragma unroll
    for (int off = 32; off > 0; off >>= 1) s += __shfl_xor(s, off, 64);
    if (lane == 0) sm[4 + wv] = s;
    __syncthreads();
    s = sm[4] + sm[5] + sm[6] + sm[7];
    float inv = 1.0f / s;
    for (int i = tid; i < NGUESS; i += 256) out[i] = expf(logits[i] - m) * inv;
}

// ---------------------------------------------------------------------------
extern "C" void kernel_launch(void* const* d_in, const int* in_sizes, int n_in,
                              void* d_out, int out_size, void* d_ws, size_t ws_size,
                              hipStream_t stream) {
    const int*   guesses   = (const int*)d_in[0];
    const int*   feedbacks = (const int*)d_in[1];
    const float* gemb      = (const float*)d_in[2];
    const float* femb      = (const float*)d_in[3];
    const float* Wih       = (const float*)d_in[4];
    const float* Whh       = (const float*)d_in[5];
    const float* bih       = (const float*)d_in[6];
    const float* bhh       = (const float*)d_in[7];
    const float* Wfc       = (const float*)d_in[8];
    const float* bfc       = (const float*)d_in[9];

    float* ws     = (float*)d_ws;
    float* xs     = ws;                              // 512*2048
    float* GX     = xs + (size_t)T_STEPS * H_DIM;    // 512*8192
    float* hbuf   = GX + (size_t)T_STEPS * G_DIM;    // 2*2048
    float* logits = hbuf + 2 * H_DIM;                // 4096
    float* out    = (float*)d_out;

    embed_kernel<<<T_STEPS, 256, 0, stream>>>(guesses, feedbacks, gemb, femb, xs);

    dim3 g2(G_DIM / 64, T_STEPS / 64);               // 128 x 8
    gx_gemm<<<g2, 256, 0, stream>>>(xs, Wih, bih, bhh, GX);

    {
        void* args[] = { (void*)&Whh, (void*)&GX, (void*)&xs, (void*)&hbuf };
        hipLaunchCooperativeKernel((const void*)lstm_loop, dim3(256), dim3(1024),
                                   args, 0, stream);
    }

    // final h parity: (T_STEPS & 1)==0 -> hbuf[0]
    fc_kernel<<<NGUESS / 16, 256, 0, stream>>>(Wfc, bfc, hbuf, logits);
    softmax_kernel<<<1, 256, 0, stream>>>(logits, out);
}

// Round 3
// 8695.213 us; speedup vs baseline: 5.4875x; 5.4875x over previous
//
#include <hip/hip_runtime.h>

#define T_STEPS 512
#define H_DIM   2048
#define G_DIM   8192   // 4*H
#define NGUESS  4096
#define NWG     256

__device__ __forceinline__ float sigf(float x) { return 1.0f / (1.0f + expf(-x)); }

// ---------------------------------------------------------------------------
// Kernel 1: gather embeddings -> xs[T][2048]
// ---------------------------------------------------------------------------
__global__ void embed_kernel(const int* __restrict__ guesses,
                             const int* __restrict__ feedbacks,
                             const float* __restrict__ gemb,
                             const float* __restrict__ femb,
                             float* __restrict__ xs) {
    int t = blockIdx.x;                      // 512 blocks
    int g = guesses[t];
    int f = feedbacks[t];
    const float4* gs = (const float4*)(gemb + (size_t)g * 1024);
    const float4* fs = (const float4*)(femb + (size_t)f * 1024);
    float4* xg = (float4*)(xs + (size_t)t * H_DIM);
    int tid = threadIdx.x;                   // 256 threads
    xg[tid]       = gs[tid];
    xg[256 + tid] = fs[tid];
}

// ---------------------------------------------------------------------------
// Kernel 2: GX[t][r] = dot(W_ih[r], xs[t]) + b_ih[r] + b_hh[r]
// ---------------------------------------------------------------------------
__global__ void gx_gemm(const float* __restrict__ xs,
                        const float* __restrict__ Wih,
                        const float* __restrict__ bih,
                        const float* __restrict__ bhh,
                        float* __restrict__ GX) {
    __shared__ float As[64][17];
    __shared__ float Bs[64][17];
    int r0 = blockIdx.x * 64;
    int t0 = blockIdx.y * 64;
    int tid = threadIdx.x;
    int tx = tid & 15;
    int ty = tid >> 4;
    int lr = tid >> 2;
    int lk = (tid & 3) * 4;
    float acc[4][4] = {};

    for (int k0 = 0; k0 < H_DIM; k0 += 16) {
        const float* xp = xs  + (size_t)(t0 + lr) * H_DIM + k0 + lk;
        const float* wp = Wih + (size_t)(r0 + lr) * H_DIM + k0 + lk;
        As[lr][lk + 0] = xp[0]; As[lr][lk + 1] = xp[1];
        As[lr][lk + 2] = xp[2]; As[lr][lk + 3] = xp[3];
        Bs[lr][lk + 0] = wp[0]; Bs[lr][lk + 1] = wp[1];
        Bs[lr][lk + 2] = wp[2]; Bs[lr][lk + 3] = wp[3];
        __syncthreads();
#pragma unroll
        for (int kk = 0; kk < 16; ++kk) {
            float a[4], b[4];
#pragma unroll
            for (int i = 0; i < 4; ++i) a[i] = As[ty * 4 + i][kk];
#pragma unroll
            for (int j = 0; j < 4; ++j) b[j] = Bs[tx * 4 + j][kk];
#pragma unroll
            for (int i = 0; i < 4; ++i)
#pragma unroll
                for (int j = 0; j < 4; ++j) acc[i][j] += a[i] * b[j];
        }
        __syncthreads();
    }
#pragma unroll
    for (int i = 0; i < 4; ++i)
#pragma unroll
        for (int j = 0; j < 4; ++j) {
            int t = t0 + ty * 4 + i;
            int r = r0 + tx * 4 + j;
            GX[(size_t)t * G_DIM + r] = acc[i][j] + bih[r] + bhh[r];
        }
}

// ---------------------------------------------------------------------------
// Kernel 3: cooperative sequential LSTM loop, W_hh register-resident,
// custom inline grid barrier (no cg::sync call boundary -> no spill).
// 256 WGs x 1024 threads, 1 WG/CU. Wave v owns gate rows 2v, 2v+1 of its
// WG's 8 units. Lane l holds row elements {j*64+l}.
// Barrier: monotonic agent-scope counter; thread 0 arrives (release RMW)
// and spins; __syncthreads() on both sides (drains vmcnt before arrival).
// ---------------------------------------------------------------------------
__global__ void __launch_bounds__(1024, 4)
lstm_loop(const float* __restrict__ Whh,
          const float* __restrict__ GX,
          const float* __restrict__ xs,
          float* __restrict__ hbuf,
          unsigned* __restrict__ bar) {
    __shared__ float h_lds[H_DIM];
    __shared__ float gates[32];

    const int wg   = blockIdx.x;        // 256
    const int base = wg * 8;            // unit base
    const int tid  = threadIdx.x;
    const int lane = tid & 63;
    const int wv   = tid >> 6;          // wave 0..15

    const int r0 = 2 * wv;
    const int r1 = 2 * wv + 1;
    const int grow0 = (r0 >> 3) * H_DIM + base + (r0 & 7);
    const int grow1 = (r1 >> 3) * H_DIM + base + (r1 & 7);

    // ---- preload W_hh rows into registers (elem j*64+lane) ----
    float w0[32], w1[32];
    {
        const float* W0 = Whh + (size_t)grow0 * H_DIM + lane;
        const float* W1 = Whh + (size_t)grow1 * H_DIM + lane;
#pragma unroll
        for (int j = 0; j < 32; ++j) {
            w0[j] = W0[j * 64];
            w1[j] = W1[j * 64];
        }
    }

    unsigned nbar = 0;

    // zero h for step 0 (hbuf parity 0)
    if (tid < 8)
        __hip_atomic_store(hbuf + base + tid, 0.0f,
                           __ATOMIC_RELAXED, __HIP_MEMORY_SCOPE_AGENT);

    // ---- grid barrier (inline) ----
#define GRID_BARRIER()                                                        \
    do {                                                                      \
        __syncthreads();                                                      \
        ++nbar;                                                               \
        if (tid == 0) {                                                       \
            __hip_atomic_fetch_add(bar, 1u, __ATOMIC_ACQ_REL,                 \
                                   __HIP_MEMORY_SCOPE_AGENT);                 \
            while (__hip_atomic_load(bar, __ATOMIC_ACQUIRE,                   \
                                     __HIP_MEMORY_SCOPE_AGENT) <              \
                   nbar * (unsigned)NWG)                                      \
                __builtin_amdgcn_s_sleep(2);                                  \
        }                                                                     \
        __syncthreads();                                                      \
    } while (0)

    GRID_BARRIER();

    for (int t = 0; t < T_STEPS; ++t) {
        const float* h  = hbuf + (size_t)(t & 1) * H_DIM;
        const float* gx = GX + (size_t)t * G_DIM;
        float gxv0 = gx[grow0];
        float gxv1 = gx[grow1];

        // stage h into LDS (agent-scope loads: cross-XCD coherent)
        {
            int i = tid;
            float v0 = __hip_atomic_load(h + i, __ATOMIC_RELAXED,
                                         __HIP_MEMORY_SCOPE_AGENT);
            float v1 = __hip_atomic_load(h + i + 1024, __ATOMIC_RELAXED,
                                         __HIP_MEMORY_SCOPE_AGENT);
            h_lds[i]        = v0;
            h_lds[i + 1024] = v1;
        }
        __syncthreads();

        float acc0 = 0.0f, acc1 = 0.0f;
#pragma unroll
        for (int j = 0; j < 32; ++j) {
            float hv = h_lds[j * 64 + lane];   // 2 lanes/bank: free
            acc0 += w0[j] * hv;
            acc1 += w1[j] * hv;
        }
#pragma unroll
        for (int off = 32; off > 0; off >>= 1) {
            acc0 += __shfl_xor(acc0, off, 64);
            acc1 += __shfl_xor(acc1, off, 64);
        }
        if (lane == 0) {
            gates[r0] = acc0 + gxv0;
            gates[r1] = acc1 + gxv1;
        }
        __syncthreads();

        if (tid < 8) {
            int u = tid;
            float gi = gates[0 * 8 + u];
            float gf = gates[1 * 8 + u];
            float gg = gates[2 * 8 + u];
            float go = gates[3 * 8 + u];
            float c_in = (t > 0) ? xs[(size_t)t * H_DIM + base + u] : 0.0f;
            float c  = sigf(gf) * c_in + sigf(gi) * tanhf(gg);
            float hn = sigf(go) * tanhf(c);
            __hip_atomic_store(hbuf + (size_t)((t + 1) & 1) * H_DIM + base + u,
                               hn, __ATOMIC_RELAXED, __HIP_MEMORY_SCOPE_AGENT);
        }
        GRID_BARRIER();
    }
#undef GRID_BARRIER
}

// ---------------------------------------------------------------------------
// Kernel 4: logits[r] = dot(W_fc[r], h) + b_fc[r]
// ---------------------------------------------------------------------------
__global__ void fc_kernel(const float* __restrict__ Wfc,
                          const float* __restrict__ bfc,
                          const float* __restrict__ h,
                          float* __restrict__ logits) {
    int wg = blockIdx.x;           // 256
    int tid = threadIdx.x;
    int lane = tid & 63, wv = tid >> 6;
    int r0 = wg * 16;
    const float4* hv = (const float4*)h;
    for (int rr = wv; rr < 16; rr += 4) {
        int r = r0 + rr;
        const float4* wrow = (const float4*)(Wfc + (size_t)r * H_DIM);
        float acc = 0.0f;
#pragma unroll
        for (int c = 0; c < 8; ++c) {
            float4 w4 = wrow[c * 64 + lane];
            float4 h4 = hv[c * 64 + lane];
            acc += w4.x * h4.x + w4.y * h4.y + w4.z * h4.z + w4.w * h4.w;
        }
#pragma unroll
        for (int off = 32; off > 0; off >>= 1) acc += __shfl_xor(acc, off, 64);
        if (lane == 0) logits[r] = acc + bfc[r];
    }
}

// ---------------------------------------------------------------------------
// Kernel 5: softmax over 4096 logits -> out
// ---------------------------------------------------------------------------
__global__ void softmax_kernel(const float* __restrict__ logits,
                               float* __restrict__ out) {
    __shared__ float sm[8];
    int tid = threadIdx.x, lane = tid & 63, wv = tid >> 6;
    float m = -1e30f;
    for (int i = tid; i < NGUESS; i += 256) m = fmaxf(m, logits[i]);
#pragma unroll
    for (int off = 32; off > 0; off >>= 1) m = fmaxf(m, __shfl_xor(m, off, 64));
    if (lane == 0) sm[wv] = m;
    __syncthreads();
    m = fmaxf(fmaxf(sm[0], sm[1]), fmaxf(sm[2], sm[3]));
    float s = 0.0f;
    for (int i = tid; i < NGUESS; i += 256) s += expf(logits[i] - m);
#pragma unroll
    for (int off = 32; off > 0; off >>= 1) s += __shfl_xor(s, off, 64);
    if (lane == 0) sm[4 + wv] = s;
    __syncthreads();
    s = sm[4] + sm[5] + sm[6] + sm[7];
    float inv = 1.0f / s;
    for (int i = tid; i < NGUESS; i += 256) out[i] = expf(logits[i] - m) * inv;
}

// ---------------------------------------------------------------------------
extern "C" void kernel_launch(void* const* d_in, const int* in_sizes, int n_in,
                              void* d_out, int out_size, void* d_ws, size_t ws_size,
                              hipStream_t stream) {
    const int*   guesses   = (const int*)d_in[0];
    const int*   feedbacks = (const int*)d_in[1];
    const float* gemb      = (const float*)d_in[2];
    const float* femb      = (const float*)d_in[3];
    const float* Wih       = (const float*)d_in[4];
    const float* Whh       = (const float*)d_in[5];
    const float* bih       = (const float*)d_in[6];
    const float* bhh       = (const float*)d_in[7];
    const float* Wfc       = (const float*)d_in[8];
    const float* bfc       = (const float*)d_in[9];

    float* ws     = (float*)d_ws;
    float* xs     = ws;                              // 512*2048
    float* GX     = xs + (size_t)T_STEPS * H_DIM;    // 512*8192
    float* hbuf   = GX + (size_t)T_STEPS * G_DIM;    // 2*2048
    float* logits = hbuf + 2 * H_DIM;                // 4096
    unsigned* bar = (unsigned*)(logits + NGUESS);    // 1 counter
    float* out    = (float*)d_out;

    // reset barrier counter every call (graph replays include this)
    hipMemsetAsync(bar, 0, sizeof(unsigned), stream);

    embed_kernel<<<T_STEPS, 256, 0, stream>>>(guesses, feedbacks, gemb, femb, xs);

    dim3 g2(G_DIM / 64, T_STEPS / 64);               // 128 x 8
    gx_gemm<<<g2, 256, 0, stream>>>(xs, Wih, bih, bhh, GX);

    {
        void* args[] = { (void*)&Whh, (void*)&GX, (void*)&xs,
                         (void*)&hbuf, (void*)&bar };
        hipLaunchCooperativeKernel((const void*)lstm_loop, dim3(NWG), dim3(1024),
                                   args, 0, stream);
    }

    // final h parity: (T_STEPS & 1)==0 -> hbuf[0]
    fc_kernel<<<NGUESS / 16, 256, 0, stream>>>(Wfc, bfc, hbuf, logits);
    softmax_kernel<<<1, 256, 0, stream>>>(logits, out);
}

// Round 4
// 1750.936 us; speedup vs baseline: 27.2511x; 4.9660x over previous
//
#include <hip/hip_runtime.h>

#define T_STEPS 512
#define H_DIM   2048
#define G_DIM   8192   // 4*H
#define NGUESS  4096
#define NWG     256

typedef unsigned long long u64;

__device__ __forceinline__ float sigf(float x) { return 1.0f / (1.0f + expf(-x)); }

// ---------------------------------------------------------------------------
// Kernel 1: gather embeddings -> xs[T][2048]
// ---------------------------------------------------------------------------
__global__ void embed_kernel(const int* __restrict__ guesses,
                             const int* __restrict__ feedbacks,
                             const float* __restrict__ gemb,
                             const float* __restrict__ femb,
                             float* __restrict__ xs) {
    int t = blockIdx.x;                      // 512 blocks
    int g = guesses[t];
    int f = feedbacks[t];
    const float4* gs = (const float4*)(gemb + (size_t)g * 1024);
    const float4* fs = (const float4*)(femb + (size_t)f * 1024);
    float4* xg = (float4*)(xs + (size_t)t * H_DIM);
    int tid = threadIdx.x;                   // 256 threads
    xg[tid]       = gs[tid];
    xg[256 + tid] = fs[tid];
}

// ---------------------------------------------------------------------------
// Kernel 2: GX[t][r] = dot(W_ih[r], xs[t]) + b_ih[r] + b_hh[r]
// ---------------------------------------------------------------------------
__global__ void gx_gemm(const float* __restrict__ xs,
                        const float* __restrict__ Wih,
                        const float* __restrict__ bih,
                        const float* __restrict__ bhh,
                        float* __restrict__ GX) {
    __shared__ float As[64][17];
    __shared__ float Bs[64][17];
    int r0 = blockIdx.x * 64;
    int t0 = blockIdx.y * 64;
    int tid = threadIdx.x;
    int tx = tid & 15;
    int ty = tid >> 4;
    int lr = tid >> 2;
    int lk = (tid & 3) * 4;
    float acc[4][4] = {};

    for (int k0 = 0; k0 < H_DIM; k0 += 16) {
        const float* xp = xs  + (size_t)(t0 + lr) * H_DIM + k0 + lk;
        const float* wp = Wih + (size_t)(r0 + lr) * H_DIM + k0 + lk;
        As[lr][lk + 0] = xp[0]; As[lr][lk + 1] = xp[1];
        As[lr][lk + 2] = xp[2]; As[lr][lk + 3] = xp[3];
        Bs[lr][lk + 0] = wp[0]; Bs[lr][lk + 1] = wp[1];
        Bs[lr][lk + 2] = wp[2]; Bs[lr][lk + 3] = wp[3];
        __syncthreads();
#pragma unroll
        for (int kk = 0; kk < 16; ++kk) {
            float a[4], b[4];
#pragma unroll
            for (int i = 0; i < 4; ++i) a[i] = As[ty * 4 + i][kk];
#pragma unroll
            for (int j = 0; j < 4; ++j) b[j] = Bs[tx * 4 + j][kk];
#pragma unroll
            for (int i = 0; i < 4; ++i)
#pragma unroll
                for (int j = 0; j < 4; ++j) acc[i][j] += a[i] * b[j];
        }
        __syncthreads();
    }
#pragma unroll
    for (int i = 0; i < 4; ++i)
#pragma unroll
        for (int j = 0; j < 4; ++j) {
            int t = t0 + ty * 4 + i;
            int r = r0 + tx * 4 + j;
            GX[(size_t)t * G_DIM + r] = acc[i][j] + bih[r] + bhh[r];
        }
}

// ---------------------------------------------------------------------------
// Kernel 3: sequential LSTM, W_hh register-resident, NO grid barrier.
// h propagated as seq-tagged 8B words: word = (step<<32)|float_bits, stored
// to a double-buffered slot (parity (t+1)&1). Consumers poll each word for
// seq==t (data IS the flag: no fences, no contended RMW). Dataflow bounds
// production skew to 1 step, so 2 slots are provably overwrite-safe.
// Slots memset to 0 each call (seq in 1..512, exact-match poll -> no ABA
// across graph replays).
// 256 WGs x 1024 threads, 1 WG/CU; wave v owns gate rows 2v, 2v+1 of its
// WG's 8 units; lane l holds W_hh row elements {j*64+l} in regs.
// ---------------------------------------------------------------------------
__global__ void __launch_bounds__(1024, 4)
lstm_loop(const float* __restrict__ Whh,
          const float* __restrict__ GX,
          const float* __restrict__ xs,
          u64* __restrict__ hseq,       // [2][H_DIM] packed (seq, value)
          float* __restrict__ hfinal) { // [H_DIM] plain float result
    __shared__ float h_lds[H_DIM];
    __shared__ float gates[32];

    const int wg   = blockIdx.x;        // 256
    const int base = wg * 8;            // unit base
    const int tid  = threadIdx.x;
    const int lane = tid & 63;
    const int wv   = tid >> 6;          // wave 0..15

    const int r0 = 2 * wv;              // gate-row indices (gate = r>>3, unit = r&7)
    const int r1 = 2 * wv + 1;
    const int grow0 = (r0 >> 3) * H_DIM + base + (r0 & 7);
    const int grow1 = (r1 >> 3) * H_DIM + base + (r1 & 7);

    // ---- preload W_hh rows into registers (elem j*64+lane) ----
    float w0[32], w1[32];
    {
        const float* W0 = Whh + (size_t)grow0 * H_DIM + lane;
        const float* W1 = Whh + (size_t)grow1 * H_DIM + lane;
#pragma unroll
        for (int j = 0; j < 32; ++j) {
            w0[j] = W0[j * 64];
            w1[j] = W1[j * 64];
        }
    }

    for (int t = 0; t < T_STEPS; ++t) {
        const float* gx = GX + (size_t)t * G_DIM;
        // issue independent loads early (latency hides under the poll)
        float gxv0 = gx[grow0];
        float gxv1 = gx[grow1];
        float c_in = 0.0f;
        if (t > 0 && tid < 8)
            c_in = xs[(size_t)t * H_DIM + base + tid];

        if (t > 0) {
            // ---- poll h(t) words, stage to LDS ----
            u64* slot = hseq + (size_t)(t & 1) * H_DIM;
            const unsigned want = (unsigned)t;
            u64 wa = __hip_atomic_load(slot + tid, __ATOMIC_RELAXED,
                                       __HIP_MEMORY_SCOPE_AGENT);
            while ((unsigned)(wa >> 32) != want) {
                __builtin_amdgcn_s_sleep(1);
                wa = __hip_atomic_load(slot + tid, __ATOMIC_RELAXED,
                                       __HIP_MEMORY_SCOPE_AGENT);
            }
            u64 wb = __hip_atomic_load(slot + tid + 1024, __ATOMIC_RELAXED,
                                       __HIP_MEMORY_SCOPE_AGENT);
            while ((unsigned)(wb >> 32) != want) {
                __builtin_amdgcn_s_sleep(1);
                wb = __hip_atomic_load(slot + tid + 1024, __ATOMIC_RELAXED,
                                       __HIP_MEMORY_SCOPE_AGENT);
            }
            h_lds[tid]        = __uint_as_float((unsigned)wa);
            h_lds[tid + 1024] = __uint_as_float((unsigned)wb);
            __syncthreads();   // B1

            // ---- dot: 2 rows per wave ----
            float acc0 = 0.0f, acc1 = 0.0f;
#pragma unroll
            for (int j = 0; j < 32; ++j) {
                float hv = h_lds[j * 64 + lane];   // 2 lanes/bank: free
                acc0 += w0[j] * hv;
                acc1 += w1[j] * hv;
            }
#pragma unroll
            for (int off = 32; off > 0; off >>= 1) {
                acc0 += __shfl_xor(acc0, off, 64);
                acc1 += __shfl_xor(acc1, off, 64);
            }
            if (lane == 0) {
                gates[r0] = acc0 + gxv0;
                gates[r1] = acc1 + gxv1;
            }
        } else {
            // h == 0: gates are just GX[0]
            if (tid < 32)
                gates[tid] = gx[(tid >> 3) * H_DIM + base + (tid & 7)];
        }
        __syncthreads();       // B2

        if (tid < 8) {
            int u = tid;
            float gi = gates[0 * 8 + u];
            float gf = gates[1 * 8 + u];
            float gg = gates[2 * 8 + u];
            float go = gates[3 * 8 + u];
            float c  = sigf(gf) * c_in + sigf(gi) * tanhf(gg);
            float hn = sigf(go) * tanhf(c);
            u64 word = ((u64)(unsigned)(t + 1) << 32) | (u64)__float_as_uint(hn);
            __hip_atomic_store(hseq + (size_t)((t + 1) & 1) * H_DIM + base + u,
                               word, __ATOMIC_RELAXED, __HIP_MEMORY_SCOPE_AGENT);
            if (t == T_STEPS - 1)
                hfinal[base + u] = hn;   // kernel-end release makes it visible
        }
        // no trailing barrier: next iteration's polls self-synchronize; gates
        // writes at t+1 are fenced by B1(t+1) which tid<8 reach after reading
        // gates, and h_lds writes at t+1 race nothing (dot reads ended at B2).
    }
}

// ---------------------------------------------------------------------------
// Kernel 4: logits[r] = dot(W_fc[r], h) + b_fc[r]
// ---------------------------------------------------------------------------
__global__ void fc_kernel(const float* __restrict__ Wfc,
                          const float* __restrict__ bfc,
                          const float* __restrict__ h,
                          float* __restrict__ logits) {
    int wg = blockIdx.x;           // 256
    int tid = threadIdx.x;
    int lane = tid & 63, wv = tid >> 6;
    int r0 = wg * 16;
    const float4* hv = (const float4*)h;
    for (int rr = wv; rr < 16; rr += 4) {
        int r = r0 + rr;
        const float4* wrow = (const float4*)(Wfc + (size_t)r * H_DIM);
        float acc = 0.0f;
#pragma unroll
        for (int c = 0; c < 8; ++c) {
            float4 w4 = wrow[c * 64 + lane];
            float4 h4 = hv[c * 64 + lane];
            acc += w4.x * h4.x + w4.y * h4.y + w4.z * h4.z + w4.w * h4.w;
        }
#pragma unroll
        for (int off = 32; off > 0; off >>= 1) acc += __shfl_xor(acc, off, 64);
        if (lane == 0) logits[r] = acc + bfc[r];
    }
}

// ---------------------------------------------------------------------------
// Kernel 5: softmax over 4096 logits -> out
// ---------------------------------------------------------------------------
__global__ void softmax_kernel(const float* __restrict__ logits,
                               float* __restrict__ out) {
    __shared__ float sm[8];
    int tid = threadIdx.x, lane = tid & 63, wv = tid >> 6;
    float m = -1e30f;
    for (int i = tid; i < NGUESS; i += 256) m = fmaxf(m, logits[i]);
#pragma unroll
    for (int off = 32; off > 0; off >>= 1) m = fmaxf(m, __shfl_xor(m, off, 64));
    if (lane == 0) sm[wv] = m;
    __syncthreads();
    m = fmaxf(fmaxf(sm[0], sm[1]), fmaxf(sm[2], sm[3]));
    float s = 0.0f;
    for (int i = tid; i < NGUESS; i += 256) s += expf(logits[i] - m);
#pragma unroll
    for (int off = 32; off > 0; off >>= 1) s += __shfl_xor(s, off, 64);
    if (lane == 0) sm[4 + wv] = s;
    __syncthreads();
    s = sm[4] + sm[5] + sm[6] + sm[7];
    float inv = 1.0f / s;
    for (int i = tid; i < NGUESS; i += 256) out[i] = expf(logits[i] - m) * inv;
}

// ---------------------------------------------------------------------------
extern "C" void kernel_launch(void* const* d_in, const int* in_sizes, int n_in,
                              void* d_out, int out_size, void* d_ws, size_t ws_size,
                              hipStream_t stream) {
    const int*   guesses   = (const int*)d_in[0];
    const int*   feedbacks = (const int*)d_in[1];
    const float* gemb      = (const float*)d_in[2];
    const float* femb      = (const float*)d_in[3];
    const float* Wih       = (const float*)d_in[4];
    const float* Whh       = (const float*)d_in[5];
    const float* bih       = (const float*)d_in[6];
    const float* bhh       = (const float*)d_in[7];
    const float* Wfc       = (const float*)d_in[8];
    const float* bfc       = (const float*)d_in[9];

    float* ws     = (float*)d_ws;
    float* xs     = ws;                              // 512*2048 f   (4 MB)
    float* GX     = xs + (size_t)T_STEPS * H_DIM;    // 512*8192 f   (16 MB)
    u64*   hseq   = (u64*)(GX + (size_t)T_STEPS * G_DIM);  // 2*2048 u64 (32 KB)
    float* hfinal = (float*)(hseq + 2 * H_DIM);      // 2048 f
    float* logits = hfinal + H_DIM;                  // 4096 f
    float* out    = (float*)d_out;

    // reset seq tags every call (graph replays include this) -> no ABA
    hipMemsetAsync(hseq, 0, 2 * H_DIM * sizeof(u64), stream);

    embed_kernel<<<T_STEPS, 256, 0, stream>>>(guesses, feedbacks, gemb, femb, xs);

    dim3 g2(G_DIM / 64, T_STEPS / 64);               // 128 x 8
    gx_gemm<<<g2, 256, 0, stream>>>(xs, Wih, bih, bhh, GX);

    {
        // cooperative launch solely for the co-residency guarantee
        void* args[] = { (void*)&Whh, (void*)&GX, (void*)&xs,
                         (void*)&hseq, (void*)&hfinal };
        hipLaunchCooperativeKernel((const void*)lstm_loop, dim3(NWG), dim3(1024),
                                   args, 0, stream);
    }

    fc_kernel<<<NGUESS / 16, 256, 0, stream>>>(Wfc, bfc, hfinal, logits);
    softmax_kernel<<<1, 256, 0, stream>>>(logits, out);
}